// Round 12
// baseline (79.622 us; speedup 1.0000x reference)
//
#include <hip/hip_runtime.h>
#include <hip/hip_bf16.h>

// Problem constants (B,C,N fixed by the reference)
#define B_ 32
#define C_ 64
#define N_ 16384
constexpr float BN_INV = 1.0f / (32.0f * 16384.0f);   // 1/(B*N)

typedef float f32x4 __attribute__((ext_vector_type(4)));
typedef short s16x8 __attribute__((ext_vector_type(8)));

// ---- workspace layout (float offsets) ----
constexpr size_t WS_GPART = 0;                               // [512][4096] per-(b,chunk) Gram partials
constexpr size_t WS_RPART = WS_GPART + (size_t)512 * 4096;   // [512][64]   rowsum partials
constexpr size_t WS_G     = WS_RPART + (size_t)512 * 64;     // [32][4096]  per-batch Gram
constexpr size_t WS_RB    = WS_G + (size_t)32 * 4096;        // [32][64]    per-batch rowsums
constexpr size_t WS_V     = WS_RB + (size_t)32 * 64;         // [32][16384] channel means
constexpr size_t WS_A     = WS_V + (size_t)32 * N_;          // [4096]      A = Wq2 diag(D) Wq (f32)
constexpr size_t WS_AVEC  = WS_A + 4096;                     // [64]        a vector
constexpr size_t WS_W     = WS_AVEC + 64;                    // [32][64]    w_b = Wc @ attnmax

__device__ constexpr int P1I[10] = {0,0,0,0,1,1,1,2,2,3};
__device__ constexpr int P1J[10] = {0,1,2,3,1,2,3,2,3,3};
__device__ constexpr int P1AT[4][4] = {{0,1,2,3},{1,4,5,6},{2,5,7,8},{3,6,8,9}};

__device__ __forceinline__ unsigned short bf16_rne_s(float f) {
    unsigned u = __float_as_uint(f);
    unsigned r = u + 0x7FFFu + ((u >> 16) & 1u);
    return (unsigned short)(r >> 16);
}
__device__ __forceinline__ float bf16f(unsigned short u) {
    return __uint_as_float(((unsigned)u) << 16);
}
// HW packed f32->bf16 (RNE), 2 values per instruction.
__device__ __forceinline__ unsigned cvt_pk_bf16(float lo, float hi) {
    unsigned r;
    asm("v_cvt_pk_bf16_f32 %0, %1, %2" : "=v"(r) : "v"(lo), "v"(hi));
    return r;
}
__device__ __forceinline__ void cvt8hi(const f32x4& a, const f32x4& b, s16x8& hi) {
    union { unsigned w[4]; s16x8 v; } u;
    u.w[0] = cvt_pk_bf16(a[0], a[1]);
    u.w[1] = cvt_pk_bf16(a[2], a[3]);
    u.w[2] = cvt_pk_bf16(b[0], b[1]);
    u.w[3] = cvt_pk_bf16(b[2], b[3]);
    hi = u.v;
}

// ============ K1: barrier-free per-wave Gram (hi bf16 MFMA) + v + rowsums ============
__global__ __launch_bounds__(512, 2) void k1(const float* __restrict__ x, float* __restrict__ ws) {
    __shared__ __align__(16) float rawb[4][10 * 256];   // 40 KB
    __shared__ float rws[8][64];
    const int t = threadIdx.x, wv = t >> 6, lane = t & 63;
    const int b = blockIdx.x >> 4, ch = blockIdx.x & 15;
    const int kg = lane >> 4, cl = lane & 15;
    const float* xb = x + ((size_t)b * C_ + cl) * N_ + ch * 1024 + kg * 8;

    f32x4 accP1[10];
    #pragma unroll
    for (int i = 0; i < 10; ++i) accP1[i] = (f32x4){0.f, 0.f, 0.f, 0.f};
    f32x4 rs = {0.f, 0.f, 0.f, 0.f};

    f32x4 cA[4], cB[4], nA[4], nB[4];
    #pragma unroll
    for (int g = 0; g < 4; ++g) {
        cA[g] = *(const f32x4*)(xb + (size_t)g * (16 * N_) + wv * 32);
        cB[g] = *(const f32x4*)(xb + (size_t)g * (16 * N_) + wv * 32 + 4);
    }

    for (int w = 0; w < 4; ++w) {
        if (w < 3) {
            const int noff = (8 * (w + 1) + wv) * 32;
            #pragma unroll
            for (int g = 0; g < 4; ++g) {
                nA[g] = *(const f32x4*)(xb + (size_t)g * (16 * N_) + noff);
                nB[g] = *(const f32x4*)(xb + (size_t)g * (16 * N_) + noff + 4);
            }
        }
        s16x8 hi[4];
        #pragma unroll
        for (int g = 0; g < 4; ++g) cvt8hi(cA[g], cB[g], hi[g]);

        f32x4 s0 = cA[0] + cA[1] + cA[2] + cA[3];
        f32x4 s1 = cB[0] + cB[1] + cB[2] + cB[3];
        #pragma unroll
        for (int m = 1; m <= 8; m <<= 1) {
            #pragma unroll
            for (int j = 0; j < 4; ++j) {
                s0[j] += __shfl_xor(s0[j], m);
                s1[j] += __shfl_xor(s1[j], m);
            }
        }
        if (cl == 0) {
            float* vp = ws + WS_V + (size_t)b * N_ + ch * 1024 + (8 * w + wv) * 32 + kg * 8;
            *(f32x4*)vp       = s0 * 0.015625f;
            *(f32x4*)(vp + 4) = s1 * 0.015625f;
        }
        #pragma unroll
        for (int g = 0; g < 4; ++g)
            rs[g] += cA[g][0] + cA[g][1] + cA[g][2] + cA[g][3]
                   + cB[g][0] + cB[g][1] + cB[g][2] + cB[g][3];

        #pragma unroll
        for (int i = 0; i < 10; ++i)
            accP1[i] = __builtin_amdgcn_mfma_f32_16x16x32_bf16(hi[P1I[i]], hi[P1J[i]], accP1[i], 0, 0, 0);

        #pragma unroll
        for (int g = 0; g < 4; ++g) { cA[g] = nA[g]; cB[g] = nB[g]; }
    }

    #pragma unroll
    for (int g = 0; g < 4; ++g) {
        rs[g] += __shfl_xor(rs[g], 16);
        rs[g] += __shfl_xor(rs[g], 32);
    }
    if (lane < 16) {
        #pragma unroll
        for (int g = 0; g < 4; ++g) rws[wv][g * 16 + lane] = rs[g];
    }

    if (wv < 4) {
        float* dst = rawb[wv];
        #pragma unroll
        for (int i = 0; i < 10; ++i) *(f32x4*)(dst + i * 256 + lane * 4) = accP1[i];
    }
    __syncthreads();
    if (wv >= 4) {
        float* dst = rawb[wv - 4];
        #pragma unroll
        for (int i = 0; i < 10; ++i) {
            f32x4 o = *(f32x4*)(dst + i * 256 + lane * 4);
            *(f32x4*)(dst + i * 256 + lane * 4) = o + accP1[i];
        }
    }
    __syncthreads();
    if (t < 64) {
        float s = 0.f;
        #pragma unroll
        for (int g = 0; g < 8; ++g) s += rws[g][t];
        ws[WS_RPART + (size_t)blockIdx.x * 64 + t] = s;
    }
    float* gp = ws + WS_GPART + (size_t)blockIdx.x * 4096;
    for (int e = t; e < 4096; e += 512) {
        const int r = e >> 6, c = e & 63;
        const int bi = r >> 4, bj = c >> 4, rr = r & 15, cc = c & 15;
        const int i1 = P1AT[bi][bj] * 256;
        const int o1 = (bi <= bj) ? (((rr >> 2) * 16 + cc) * 4 + (rr & 3))
                                  : (((cc >> 2) * 16 + rr) * 4 + (cc & 3));
        gp[e] = rawb[0][i1 + o1] + rawb[1][i1 + o1] + rawb[2][i1 + o1] + rawb[3][i1 + o1];
    }
}

// ============ K2a: reduce chunk partials -> per-batch G, r ============
__global__ __launch_bounds__(256) void k2a(float* __restrict__ ws) {
    const int b = blockIdx.x >> 3, sl = blockIdx.x & 7, t = threadIdx.x;
    #pragma unroll
    for (int h = 0; h < 2; ++h) {
        const int e = sl * 512 + h * 256 + t;
        float s = 0.f;
        for (int chn = 0; chn < 16; ++chn) s += ws[WS_GPART + ((size_t)(b * 16 + chn)) * 4096 + e];
        ws[WS_G + (size_t)b * 4096 + e] = s;
    }
    if (sl == 0 && t < 64) {
        float s = 0.f;
        for (int chn = 0; chn < 16; ++chn) s += ws[WS_RPART + (size_t)(b * 16 + chn) * 64 + t];
        ws[WS_RB + b * 64 + t] = s;
    }
}

// ============ K2s: GLOBAL stats, computed ONCE (1 block) ============
// Gbar -> quad/D -> A = Wq2 diag(D) Wq -> WS_A (f32); avec -> WS_AVEC.
__global__ __launch_bounds__(256) void k2s(const float* __restrict__ Wq, const float* __restrict__ gamma,
                                           const float* __restrict__ beta, const float* __restrict__ Wq2,
                                           const float* __restrict__ bq2, float* __restrict__ ws) {
    __shared__ __align__(16) unsigned short OPH0[64 * 72], OPH1[64 * 72], OPH2[64 * 72];
    __shared__ float F1[64 * 65];
    __shared__ float mS[64], muS[64], DS[64], abv[64], quadS[64];
    const int t = threadIdx.x;
    const int w = t >> 6, lane = t & 63, cl = lane & 15, jg = lane >> 4;
    const int sr = t >> 2, sc0 = (t & 3) * 16;

    // ---- P0: Gbar -> OPH0; Wq -> F1+OPH1; Wq2 -> OPH2; m -> mS ----
    {
        f32x4 s[4];
        #pragma unroll
        for (int j = 0; j < 4; ++j) s[j] = (f32x4){0.f, 0.f, 0.f, 0.f};
        #pragma unroll 4
        for (int b = 0; b < 32; ++b) {
            const float* gbp = ws + WS_G + (size_t)b * 4096 + sr * 64 + sc0;
            #pragma unroll
            for (int j = 0; j < 4; ++j) s[j] += *(const f32x4*)(gbp + 4 * j);
        }
        s16x8 h8[2];
        #pragma unroll
        for (int q = 0; q < 2; ++q)
            #pragma unroll
            for (int j = 0; j < 8; ++j)
                h8[q][j] = (short)bf16_rne_s(s[q * 2 + (j >> 2)][j & 3] * BN_INV);
        *(s16x8*)(&OPH0[sr * 72 + sc0])     = h8[0];
        *(s16x8*)(&OPH0[sr * 72 + sc0 + 8]) = h8[1];
    }
    {
        const float* src = Wq + sr * 64 + sc0;
        s16x8 h8[2];
        #pragma unroll
        for (int q = 0; q < 2; ++q) {
            f32x4 a = *(const f32x4*)(src + q * 8);
            f32x4 b = *(const f32x4*)(src + q * 8 + 4);
            #pragma unroll
            for (int j = 0; j < 8; ++j) {
                float v = (j < 4) ? a[j] : b[j - 4];
                F1[sr * 65 + sc0 + q * 8 + j] = v;
                h8[q][j] = (short)bf16_rne_s(v);
            }
        }
        *(s16x8*)(&OPH1[sr * 72 + sc0])     = h8[0];
        *(s16x8*)(&OPH1[sr * 72 + sc0 + 8]) = h8[1];
    }
    {
        const float* src = Wq2 + sr * 64 + sc0;
        s16x8 h8[2];
        #pragma unroll
        for (int q = 0; q < 2; ++q) {
            f32x4 a = *(const f32x4*)(src + q * 8);
            f32x4 b = *(const f32x4*)(src + q * 8 + 4);
            #pragma unroll
            for (int j = 0; j < 8; ++j)
                h8[q][j] = (short)bf16_rne_s((j < 4) ? a[j] : b[j - 4]);
        }
        *(s16x8*)(&OPH2[sr * 72 + sc0])     = h8[0];
        *(s16x8*)(&OPH2[sr * 72 + sc0 + 8]) = h8[1];
    }
    if (t < 64) {
        float sm = 0.f;
        #pragma unroll 8
        for (int b = 0; b < 32; ++b) sm += ws[WS_RB + b * 64 + t];
        mS[t] = sm * BN_INV;
    }
    __syncthreads();

    auto mm64 = [&](const unsigned short* AH, const unsigned short* BH, f32x4 acc[4]) {
        #pragma unroll
        for (int ks = 0; ks < 2; ++ks) {
            const int ko = ks * 32 + jg * 8;
            s16x8 ah = *(const s16x8*)(AH + (16 * w + cl) * 72 + ko);
            #pragma unroll
            for (int bj = 0; bj < 4; ++bj) {
                s16x8 bh = *(const s16x8*)(BH + (16 * bj + cl) * 72 + ko);
                acc[bj] = __builtin_amdgcn_mfma_f32_16x16x32_bf16(ah, bh, acc[bj], 0, 0, 0);
            }
        }
    };
    // acc element (bj, j) sits at (row = 16w + jg*4 + j, col = 16bj + cl)

    // ---- P1: Y = Wq·Gbar; quad_o = rowdot(Y, Wq); mu0 = Wq·m ----
    {
        f32x4 acc[4];
        #pragma unroll
        for (int i = 0; i < 4; ++i) acc[i] = (f32x4){0.f, 0.f, 0.f, 0.f};
        mm64(OPH1, OPH0, acc);
        float s[4] = {0.f, 0.f, 0.f, 0.f};
        #pragma unroll
        for (int j = 0; j < 4; ++j) {
            const int row = 16 * w + jg * 4 + j;
            #pragma unroll
            for (int bj = 0; bj < 4; ++bj) s[j] += acc[bj][j] * F1[row * 65 + 16 * bj + cl];
        }
        #pragma unroll
        for (int m = 1; m <= 8; m <<= 1)
            #pragma unroll
            for (int j = 0; j < 4; ++j) s[j] += __shfl_xor(s[j], m);
        if (cl == 0) {
            #pragma unroll
            for (int j = 0; j < 4; ++j) quadS[16 * w + jg * 4 + j] = s[j];
        }
        if (t < 64) {
            float s2 = 0.f;
            #pragma unroll 8
            for (int c = 0; c < 64; ++c) s2 += F1[t * 65 + c] * mS[c];
            muS[t] = s2;
        }
    }
    __syncthreads();

    // ---- P2: D, abv; OPH0 := (D∘Wq)^T; avec = Wq2·abv + bq2 ----
    if (t < 64) {
        const float var = quadS[t] - muS[t] * muS[t];
        const float D = gamma[t] * rsqrtf(var + 1e-5f);
        DS[t] = D;
        abv[t] = beta[t] - D * muS[t];
    }
    __syncthreads();
    {
        s16x8 h8[2];
        #pragma unroll
        for (int q = 0; q < 2; ++q)
            #pragma unroll
            for (int j = 0; j < 8; ++j) {
                const int c = sc0 + q * 8 + j;
                h8[q][j] = (short)bf16_rne_s(DS[c] * F1[c * 65 + sr]);
            }
        *(s16x8*)(&OPH0[sr * 72 + sc0])     = h8[0];
        *(s16x8*)(&OPH0[sr * 72 + sc0 + 8]) = h8[1];
    }
    if (t < 64) {
        float s = 0.f;
        #pragma unroll 8
        for (int k = 0; k < 64; ++k) s += bf16f(OPH2[t * 72 + k]) * abv[k];
        ws[WS_AVEC + t] = s + bq2[t];
    }
    __syncthreads();

    // ---- P3: A = Wq2·(DWq) -> WS_A (f32) ----
    {
        f32x4 acc[4];
        #pragma unroll
        for (int i = 0; i < 4; ++i) acc[i] = (f32x4){0.f, 0.f, 0.f, 0.f};
        mm64(OPH2, OPH0, acc);
        #pragma unroll
        for (int bj = 0; bj < 4; ++bj)
            #pragma unroll
            for (int j = 0; j < 4; ++j) {
                const int row = 16 * w + jg * 4 + j, col = 16 * bj + cl;
                ws[WS_A + row * 64 + col] = acc[bj][j];
            }
    }
}

// ============ K2c: PER-BATCH attn chain (32 blocks, 3 barriers) ============
// Stage A/G_b/Wsr -> T = A·G_b -> R = T·S^T + rank1 -> rowmax -> w.
__global__ __launch_bounds__(256) void k2c(const float* __restrict__ Wsr, const float* __restrict__ bsr,
                                           const float* __restrict__ Wc, float* __restrict__ ws) {
    __shared__ __align__(16) unsigned short OPA[64 * 72], OPG[64 * 72], OPS[64 * 72], OPT[64 * 72];
    __shared__ float rl[64], avs[64], sbv[64], ul[64], pls[64], aml[64];
    const int bb = blockIdx.x, t = threadIdx.x;
    const int w = t >> 6, lane = t & 63, cl = lane & 15, jg = lane >> 4;
    const int sr = t >> 2, sc0 = (t & 3) * 16;

    // ---- Ph1: stage everything (all loads issued up front) ----
    {
        const float* asrc = ws + WS_A + sr * 64 + sc0;
        const float* gsrc = ws + WS_G + (size_t)bb * 4096 + sr * 64 + sc0;
        const float* ssrc = Wsr + sr * 64 + sc0;
        f32x4 av[4], gv[4], sv[4];
        #pragma unroll
        for (int j = 0; j < 4; ++j) {
            av[j] = *(const f32x4*)(asrc + 4 * j);
            gv[j] = *(const f32x4*)(gsrc + 4 * j);
            sv[j] = *(const f32x4*)(ssrc + 4 * j);
        }
        s16x8 ha[2], hg[2], hs[2];
        #pragma unroll
        for (int q = 0; q < 2; ++q)
            #pragma unroll
            for (int j = 0; j < 8; ++j) {
                const int ji = q * 2 + (j >> 2), jj = j & 3;
                ha[q][j] = (short)bf16_rne_s(av[ji][jj]);
                hg[q][j] = (short)bf16_rne_s(gv[ji][jj]);
                hs[q][j] = (short)bf16_rne_s(sv[ji][jj]);
            }
        *(s16x8*)(&OPA[sr * 72 + sc0])     = ha[0];
        *(s16x8*)(&OPA[sr * 72 + sc0 + 8]) = ha[1];
        *(s16x8*)(&OPG[sr * 72 + sc0])     = hg[0];
        *(s16x8*)(&OPG[sr * 72 + sc0 + 8]) = hg[1];
        *(s16x8*)(&OPS[sr * 72 + sc0])     = hs[0];
        *(s16x8*)(&OPS[sr * 72 + sc0 + 8]) = hs[1];
    }
    if (t < 64) {
        rl[t]  = ws[WS_RB + bb * 64 + t];
        avs[t] = ws[WS_AVEC + t];
        sbv[t] = bsr[t];
    }
    __syncthreads();

    auto mm64 = [&](const unsigned short* AH, const unsigned short* BH, f32x4 acc[4]) {
        #pragma unroll
        for (int ks = 0; ks < 2; ++ks) {
            const int ko = ks * 32 + jg * 8;
            s16x8 ah = *(const s16x8*)(AH + (16 * w + cl) * 72 + ko);
            #pragma unroll
            for (int bj = 0; bj < 4; ++bj) {
                s16x8 bh = *(const s16x8*)(BH + (16 * bj + cl) * 72 + ko);
                acc[bj] = __builtin_amdgcn_mfma_f32_16x16x32_bf16(ah, bh, acc[bj], 0, 0, 0);
            }
        }
    };
    // acc element (bj, j) sits at (row = 16w + jg*4 + j, col = 16bj + cl)

    // ---- Ph2: T = A·G_b (all waves); u (wave1); pls (wave2) ----
    {
        f32x4 accT[4];
        #pragma unroll
        for (int i = 0; i < 4; ++i) accT[i] = (f32x4){0.f, 0.f, 0.f, 0.f};
        mm64(OPA, OPG, accT);
        if (w == 1) {            // u = A r  (bf16 A from LDS)
            const int d = t - 64;
            float s = 0.f;
            #pragma unroll 8
            for (int k = 0; k < 64; ++k) s += bf16f(OPA[d * 72 + k]) * rl[k];
            ul[d] = s;
        } else if (w == 2) {     // pls = S r + N*bsr
            const int d = t - 128;
            float s = 0.f;
            #pragma unroll 8
            for (int k = 0; k < 64; ++k) s += bf16f(OPS[d * 72 + k]) * rl[k];
            pls[d] = s + 16384.f * sbv[d];
        }
        #pragma unroll
        for (int bj = 0; bj < 4; ++bj)
            #pragma unroll
            for (int j = 0; j < 4; ++j) {
                const int row = 16 * w + jg * 4 + j, col = 16 * bj + cl;
                OPT[row * 72 + col] = (unsigned short)bf16_rne_s(accT[bj][j]);
            }
    }
    __syncthreads();

    // ---- Ph3: R = T·S^T + rank1; rowmax -> aml ----
    {
        f32x4 acc[4];
        #pragma unroll
        for (int i = 0; i < 4; ++i) acc[i] = (f32x4){0.f, 0.f, 0.f, 0.f};
        mm64(OPT, OPS, acc);
        float mx[4] = {-3.4e38f, -3.4e38f, -3.4e38f, -3.4e38f};
        #pragma unroll
        for (int j = 0; j < 4; ++j) {
            const int row = 16 * w + jg * 4 + j;
            const float ur = ul[row], ar = avs[row];
            #pragma unroll
            for (int bj = 0; bj < 4; ++bj) {
                const int col = 16 * bj + cl;
                const float v = acc[bj][j] + ur * sbv[col] + ar * pls[col];
                mx[j] = fmaxf(mx[j], v);
            }
        }
        #pragma unroll
        for (int m = 1; m <= 8; m <<= 1)
            #pragma unroll
            for (int j = 0; j < 4; ++j) mx[j] = fmaxf(mx[j], __shfl_xor(mx[j], m));
        if (cl == 0) {
            #pragma unroll
            for (int j = 0; j < 4; ++j) aml[16 * w + jg * 4 + j] = mx[j];
        }
    }
    __syncthreads();

    // ---- Ph4: w_b = Wc·aml ----
    if (t < 64) {
        float s = 0.f;
        #pragma unroll 8
        for (int c = 0; c < 64; ++c) s += Wc[t * 64 + c] * aml[c];
        ws[WS_W + bb * 64 + t] = s;
    }
}

// ============ K3: out[b,o,n] = w[b,o] * v[b,n] (nontemporal, 2048 blocks) ============
__global__ __launch_bounds__(256) void k3(const float* __restrict__ ws, float* __restrict__ out) {
    const int blk = blockIdx.x;
    const int b = blk >> 6, seg = blk & 63;
    const int r0 = (seg >> 4) * 16, chk = seg & 15;
    __shared__ float wls[16];
    const int t = threadIdx.x;
    if (t < 16) wls[t] = ws[WS_W + b * 64 + r0 + t];
    __syncthreads();
    const size_t nb = (size_t)chk * 1024 + 4 * t;
    const f32x4 v4 = *(const f32x4*)(ws + WS_V + (size_t)b * N_ + nb);
    float* ob = out + ((size_t)b * C_ + r0) * N_ + nb;
    #pragma unroll
    for (int o = 0; o < 16; ++o) {
        __builtin_nontemporal_store(v4 * wls[o], (f32x4*)(ob + (size_t)o * N_));
    }
}

extern "C" void kernel_launch(void* const* d_in, const int* in_sizes, int n_in,
                              void* d_out, int out_size, void* d_ws, size_t ws_size,
                              hipStream_t stream) {
    const float* x     = (const float*)d_in[0];
    const float* Wq    = (const float*)d_in[1];
    const float* gamma = (const float*)d_in[3];
    const float* beta  = (const float*)d_in[4];
    const float* Wq2   = (const float*)d_in[5];
    const float* bq2   = (const float*)d_in[6];
    const float* Wsr   = (const float*)d_in[7];
    const float* bsr   = (const float*)d_in[8];
    const float* Wc    = (const float*)d_in[9];
    float* ws  = (float*)d_ws;
    float* out = (float*)d_out;

    hipLaunchKernelGGL(k1,  dim3(512),  dim3(512), 0, stream, x, ws);
    hipLaunchKernelGGL(k2a, dim3(256),  dim3(256), 0, stream, ws);
    hipLaunchKernelGGL(k2s, dim3(1),    dim3(256), 0, stream, Wq, gamma, beta, Wq2, bq2, ws);
    hipLaunchKernelGGL(k2c, dim3(32),   dim3(256), 0, stream, Wsr, bsr, Wc, ws);
    hipLaunchKernelGGL(k3,  dim3(2048), dim3(256), 0, stream, ws, out);
}

// Round 14
// 68.915 us; speedup vs baseline: 1.1554x; 1.1554x over previous
//
#include <hip/hip_runtime.h>
#include <hip/hip_bf16.h>

// Problem constants (B,C,N fixed by the reference)
#define B_ 32
#define C_ 64
#define N_ 16384
constexpr float BN_INV = 1.0f / (32.0f * 16384.0f);   // 1/(B*N)

typedef float f32x4 __attribute__((ext_vector_type(4)));
typedef short s16x8 __attribute__((ext_vector_type(8)));

// ---- workspace layout (float offsets) ----
constexpr size_t WS_GPART = 0;                               // [512][4096] per-(b,chunk) Gram partials
constexpr size_t WS_RPART = WS_GPART + (size_t)512 * 4096;   // [512][64]   rowsum partials
constexpr size_t WS_G     = WS_RPART + (size_t)512 * 64;     // [32][4096]  per-batch Gram
constexpr size_t WS_RB    = WS_G + (size_t)32 * 4096;        // [32][64]    per-batch rowsums
constexpr size_t WS_V     = WS_RB + (size_t)32 * 64;         // [32][16384] channel means
constexpr size_t WS_W     = WS_V + (size_t)32 * N_;          // [32][64]    w_b
constexpr size_t WS_GBAR  = WS_W + (size_t)32 * 64;          // [4096] raw sum of all G (atomics)
constexpr size_t WS_MBAR  = WS_GBAR + 4096;                  // [64]   raw sum of all rowsums

__device__ constexpr int P1I[10] = {0,0,0,0,1,1,1,2,2,3};
__device__ constexpr int P1J[10] = {0,1,2,3,1,2,3,2,3,3};
__device__ constexpr int P1AT[4][4] = {{0,1,2,3},{1,4,5,6},{2,5,7,8},{3,6,8,9}};

__device__ __forceinline__ unsigned short bf16_rne_s(float f) {
    unsigned u = __float_as_uint(f);
    unsigned r = u + 0x7FFFu + ((u >> 16) & 1u);
    return (unsigned short)(r >> 16);
}
__device__ __forceinline__ float bf16f(unsigned short u) {
    return __uint_as_float(((unsigned)u) << 16);
}
__device__ __forceinline__ unsigned cvt_pk_bf16(float lo, float hi) {
    unsigned r;
    asm("v_cvt_pk_bf16_f32 %0, %1, %2" : "=v"(r) : "v"(lo), "v"(hi));
    return r;
}
__device__ __forceinline__ void cvt8hi(const f32x4& a, const f32x4& b, s16x8& hi) {
    union { unsigned w[4]; s16x8 v; } u;
    u.w[0] = cvt_pk_bf16(a[0], a[1]);
    u.w[1] = cvt_pk_bf16(a[2], a[3]);
    u.w[2] = cvt_pk_bf16(b[0], b[1]);
    u.w[3] = cvt_pk_bf16(b[2], b[3]);
    hi = u.v;
}

// ============ K1: barrier-free per-wave Gram (hi bf16 MFMA) + v + rowsums ============
__global__ __launch_bounds__(512, 2) void k1(const float* __restrict__ x, float* __restrict__ ws) {
    __shared__ __align__(16) float rawb[4][10 * 256];   // 40 KB
    __shared__ float rws[8][64];
    const int t = threadIdx.x, wv = t >> 6, lane = t & 63;
    const int b = blockIdx.x >> 4, ch = blockIdx.x & 15;
    const int kg = lane >> 4, cl = lane & 15;
    const float* xb = x + ((size_t)b * C_ + cl) * N_ + ch * 1024 + kg * 8;

    // zero the atomic accumulators for this call (k2a adds into them next dispatch)
    if (blockIdx.x == 0) {
        #pragma unroll
        for (int i = 0; i < 8; ++i) ws[WS_GBAR + t * 8 + i] = 0.f;
        if (t < 64) ws[WS_MBAR + t] = 0.f;
    }

    f32x4 accP1[10];
    #pragma unroll
    for (int i = 0; i < 10; ++i) accP1[i] = (f32x4){0.f, 0.f, 0.f, 0.f};
    f32x4 rs = {0.f, 0.f, 0.f, 0.f};

    f32x4 cA[4], cB[4], nA[4], nB[4];
    #pragma unroll
    for (int g = 0; g < 4; ++g) {
        cA[g] = *(const f32x4*)(xb + (size_t)g * (16 * N_) + wv * 32);
        cB[g] = *(const f32x4*)(xb + (size_t)g * (16 * N_) + wv * 32 + 4);
    }

    for (int w = 0; w < 4; ++w) {
        if (w < 3) {
            const int noff = (8 * (w + 1) + wv) * 32;
            #pragma unroll
            for (int g = 0; g < 4; ++g) {
                nA[g] = *(const f32x4*)(xb + (size_t)g * (16 * N_) + noff);
                nB[g] = *(const f32x4*)(xb + (size_t)g * (16 * N_) + noff + 4);
            }
        }
        s16x8 hi[4];
        #pragma unroll
        for (int g = 0; g < 4; ++g) cvt8hi(cA[g], cB[g], hi[g]);

        f32x4 s0 = cA[0] + cA[1] + cA[2] + cA[3];
        f32x4 s1 = cB[0] + cB[1] + cB[2] + cB[3];
        #pragma unroll
        for (int m = 1; m <= 8; m <<= 1) {
            #pragma unroll
            for (int j = 0; j < 4; ++j) {
                s0[j] += __shfl_xor(s0[j], m);
                s1[j] += __shfl_xor(s1[j], m);
            }
        }
        if (cl == 0) {
            float* vp = ws + WS_V + (size_t)b * N_ + ch * 1024 + (8 * w + wv) * 32 + kg * 8;
            *(f32x4*)vp       = s0 * 0.015625f;
            *(f32x4*)(vp + 4) = s1 * 0.015625f;
        }
        #pragma unroll
        for (int g = 0; g < 4; ++g)
            rs[g] += cA[g][0] + cA[g][1] + cA[g][2] + cA[g][3]
                   + cB[g][0] + cB[g][1] + cB[g][2] + cB[g][3];

        #pragma unroll
        for (int i = 0; i < 10; ++i)
            accP1[i] = __builtin_amdgcn_mfma_f32_16x16x32_bf16(hi[P1I[i]], hi[P1J[i]], accP1[i], 0, 0, 0);

        #pragma unroll
        for (int g = 0; g < 4; ++g) { cA[g] = nA[g]; cB[g] = nB[g]; }
    }

    #pragma unroll
    for (int g = 0; g < 4; ++g) {
        rs[g] += __shfl_xor(rs[g], 16);
        rs[g] += __shfl_xor(rs[g], 32);
    }
    if (lane < 16) {
        #pragma unroll
        for (int g = 0; g < 4; ++g) rws[wv][g * 16 + lane] = rs[g];
    }

    if (wv < 4) {
        float* dst = rawb[wv];
        #pragma unroll
        for (int i = 0; i < 10; ++i) *(f32x4*)(dst + i * 256 + lane * 4) = accP1[i];
    }
    __syncthreads();
    if (wv >= 4) {
        float* dst = rawb[wv - 4];
        #pragma unroll
        for (int i = 0; i < 10; ++i) {
            f32x4 o = *(f32x4*)(dst + i * 256 + lane * 4);
            *(f32x4*)(dst + i * 256 + lane * 4) = o + accP1[i];
        }
    }
    __syncthreads();
    if (t < 64) {
        float s = 0.f;
        #pragma unroll
        for (int g = 0; g < 8; ++g) s += rws[g][t];
        ws[WS_RPART + (size_t)blockIdx.x * 64 + t] = s;
    }
    float* gp = ws + WS_GPART + (size_t)blockIdx.x * 4096;
    for (int e = t; e < 4096; e += 512) {
        const int r = e >> 6, c = e & 63;
        const int bi = r >> 4, bj = c >> 4, rr = r & 15, cc = c & 15;
        const int i1 = P1AT[bi][bj] * 256;
        const int o1 = (bi <= bj) ? (((rr >> 2) * 16 + cc) * 4 + (rr & 3))
                                  : (((cc >> 2) * 16 + rr) * 4 + (cc & 3));
        gp[e] = rawb[0][i1 + o1] + rawb[1][i1 + o1] + rawb[2][i1 + o1] + rawb[3][i1 + o1];
    }
}

// ============ K2a: reduce chunk partials -> per-batch G, r; atomics -> Gbar, Mbar ============
__global__ __launch_bounds__(256) void k2a(float* __restrict__ ws) {
    const int b = blockIdx.x >> 3, sl = blockIdx.x & 7, t = threadIdx.x;
    #pragma unroll
    for (int h = 0; h < 2; ++h) {
        const int e = sl * 512 + h * 256 + t;
        float s = 0.f;
        for (int chn = 0; chn < 16; ++chn) s += ws[WS_GPART + ((size_t)(b * 16 + chn)) * 4096 + e];
        ws[WS_G + (size_t)b * 4096 + e] = s;
        unsafeAtomicAdd(ws + WS_GBAR + e, s);
    }
    if (sl == 0 && t < 64) {
        float s = 0.f;
        for (int chn = 0; chn < 16; ++chn) s += ws[WS_RPART + (size_t)(b * 16 + chn) * 64 + t];
        ws[WS_RB + b * 64 + t] = s;
        unsafeAtomicAdd(ws + WS_MBAR + t, s);
    }
}

// ============ K2b: C×C chain, 5 barriers, wave-specialized (32 blocks) ============
// LDS slots: 0=Gbar->DWqT, 1=Wq->A, 2=Wq2, 3=G_b, 4=Wsr, 5=SG (= S·G_b = (G_b·S^T)^T)
__global__ __launch_bounds__(256) void k2b(const float* __restrict__ Wq, const float* __restrict__ gamma,
                                           const float* __restrict__ beta, const float* __restrict__ Wq2,
                                           const float* __restrict__ bq2, const float* __restrict__ Wsr,
                                           const float* __restrict__ bsr, const float* __restrict__ Wc,
                                           float* __restrict__ ws) {
    __shared__ __align__(16) unsigned short OPH[6][64 * 72];   // 55.3 KB
    __shared__ float quadS[64], muS[64], DS[64], abv[64], mS[64];
    __shared__ float rl[64], ul[64], avs[64], sbv[64], pls[64], aml[64];
    const int bb = blockIdx.x, t = threadIdx.x;
    const int w = t >> 6, lane = t & 63, cl = lane & 15, jg = lane >> 4;
    const int sr = t >> 2, sc0 = (t & 3) * 16;

    // ---- stage all 5 matrices + vectors (loads issued up front) ----
    {
        const float* srcs[5] = { ws + WS_GBAR, Wq, Wq2, ws + WS_G + (size_t)bb * 4096, Wsr };
        #pragma unroll
        for (int mI = 0; mI < 5; ++mI) {
            const float sc = (mI == 0) ? BN_INV : 1.f;
            const float* src = srcs[mI] + sr * 64 + sc0;
            s16x8 h8[2];
            #pragma unroll
            for (int q = 0; q < 2; ++q) {
                f32x4 a = *(const f32x4*)(src + q * 8);
                f32x4 b2 = *(const f32x4*)(src + q * 8 + 4);
                #pragma unroll
                for (int j = 0; j < 8; ++j)
                    h8[q][j] = (short)bf16_rne_s(((j < 4) ? a[j] : b2[j - 4]) * sc);
            }
            *(s16x8*)(&OPH[mI][sr * 72 + sc0])     = h8[0];
            *(s16x8*)(&OPH[mI][sr * 72 + sc0 + 8]) = h8[1];
        }
    }
    if (t < 64) {
        mS[t]  = ws[WS_MBAR + t] * BN_INV;
        rl[t]  = ws[WS_RB + bb * 64 + t];
        sbv[t] = bsr[t];
    }
    __syncthreads();

    // one 16-row stripe of a 64x64 matmul: computes C = Arows · Brows^T, i.e. C[r][c] = sum_k A[r][k]·B[c][k]
    auto mmStripe = [&](const unsigned short* AH, const unsigned short* BH, int row0, f32x4* acc) {
        #pragma unroll
        for (int ks = 0; ks < 2; ++ks) {
            const int ko = ks * 32 + jg * 8;
            s16x8 ah = *(const s16x8*)(AH + (row0 + cl) * 72 + ko);
            #pragma unroll
            for (int bj = 0; bj < 4; ++bj) {
                s16x8 bh = *(const s16x8*)(BH + (16 * bj + cl) * 72 + ko);
                acc[bj] = __builtin_amdgcn_mfma_f32_16x16x32_bf16(ah, bh, acc[bj], 0, 0, 0);
            }
        }
    };
    // acc element (bj, j) = C[row0 + jg*4 + j][16bj + cl]

    // ---- Ph1: waves 0-1: Y = Wq·Gbar -> quad; mu0.  waves 2-3: SG = Wsr·G_b^T (=S·G_b); pls ----
    if (w < 2) {
        f32x4 acc2[2][4];
        #pragma unroll
        for (int st = 0; st < 2; ++st)
            #pragma unroll
            for (int i = 0; i < 4; ++i) acc2[st][i] = (f32x4){0.f, 0.f, 0.f, 0.f};
        mmStripe(OPH[1], OPH[0], 32 * w,      acc2[0]);   // Gbar symmetric -> Wq·Gbar
        mmStripe(OPH[1], OPH[0], 32 * w + 16, acc2[1]);
        #pragma unroll
        for (int st = 0; st < 2; ++st) {
            float s[4] = {0.f, 0.f, 0.f, 0.f};
            #pragma unroll
            for (int j = 0; j < 4; ++j) {
                const int row = 32 * w + 16 * st + jg * 4 + j;
                #pragma unroll
                for (int bj = 0; bj < 4; ++bj)
                    s[j] += acc2[st][bj][j] * bf16f(OPH[1][row * 72 + 16 * bj + cl]);
            }
            #pragma unroll
            for (int m = 1; m <= 8; m <<= 1)
                #pragma unroll
                for (int j = 0; j < 4; ++j) s[j] += __shfl_xor(s[j], m);
            if (cl == 0) {
                #pragma unroll
                for (int j = 0; j < 4; ++j) quadS[32 * w + 16 * st + jg * 4 + j] = s[j];
            }
        }
        if (t < 64) {   // mu0 = Wq·m (bf16 Wq)
            float s2 = 0.f;
            #pragma unroll 8
            for (int c = 0; c < 64; ++c) s2 += bf16f(OPH[1][t * 72 + c]) * mS[c];
            muS[t] = s2;
        }
    } else {
        const int w2 = w - 2;
        f32x4 acc2[2][4];
        #pragma unroll
        for (int st = 0; st < 2; ++st)
            #pragma unroll
            for (int i = 0; i < 4; ++i) acc2[st][i] = (f32x4){0.f, 0.f, 0.f, 0.f};
        // SG = Wsr·G_b^T = S·G_b (G symmetric). Stored row-major; Ph4's A·SG^T then gives A·G·S^T.
        mmStripe(OPH[4], OPH[3], 32 * w2,      acc2[0]);
        mmStripe(OPH[4], OPH[3], 32 * w2 + 16, acc2[1]);
        #pragma unroll
        for (int st = 0; st < 2; ++st)
            #pragma unroll
            for (int bj = 0; bj < 4; ++bj)
                #pragma unroll
                for (int j = 0; j < 4; ++j) {
                    const int row = 32 * w2 + 16 * st + jg * 4 + j, col = 16 * bj + cl;
                    OPH[5][row * 72 + col] = (unsigned short)bf16_rne_s(acc2[st][bj][j]);
                }
        const int t2 = t - 128;
        if (t2 < 64) {   // pls = Wsr·r + N·bsr
            float s = 0.f;
            #pragma unroll 8
            for (int k = 0; k < 64; ++k) s += bf16f(OPH[4][t2 * 72 + k]) * rl[k];
            pls[t2] = s + 16384.f * sbv[t2];
        }
    }
    __syncthreads();

    // ---- Ph2: D; DWq^T -> slot0; avec ----
    if (t < 64) {
        const float var = quadS[t] - muS[t] * muS[t];
        const float D = gamma[t] * rsqrtf(var + 1e-5f);
        DS[t] = D;
        abv[t] = beta[t] - D * muS[t];
    }
    __syncthreads();
    {
        #pragma unroll
        for (int q = 0; q < 2; ++q) {
            s16x8 h8;
            #pragma unroll
            for (int j = 0; j < 8; ++j) {
                const int c = sc0 + q * 8 + j;
                h8[j] = (short)bf16_rne_s(DS[c] * bf16f(OPH[1][c * 72 + sr]));
            }
            *(s16x8*)(&OPH[0][sr * 72 + sc0 + q * 8]) = h8;
        }
    }
    if (t < 64) {
        float s = 0.f;
        #pragma unroll 8
        for (int k = 0; k < 64; ++k) s += bf16f(OPH[2][t * 72 + k]) * abv[k];
        avs[t] = s + bq2[t];
    }
    __syncthreads();

    // ---- Ph3: A = Wq2·(DWq); u = A·r (in-register rowdot); A -> slot1 ----
    {
        f32x4 accA[4];
        #pragma unroll
        for (int i = 0; i < 4; ++i) accA[i] = (f32x4){0.f, 0.f, 0.f, 0.f};
        mmStripe(OPH[2], OPH[0], 16 * w, accA);   // slot0[c][k] = D[k]Wq[k][c] -> A = Wq2·diag(D)·Wq
        float su[4] = {0.f, 0.f, 0.f, 0.f};
        #pragma unroll
        for (int bj = 0; bj < 4; ++bj) {
            const float cv = rl[16 * bj + cl];
            #pragma unroll
            for (int j = 0; j < 4; ++j) su[j] += accA[bj][j] * cv;
        }
        #pragma unroll
        for (int m = 1; m <= 8; m <<= 1)
            #pragma unroll
            for (int j = 0; j < 4; ++j) su[j] += __shfl_xor(su[j], m);
        if (cl == 0) {
            #pragma unroll
            for (int j = 0; j < 4; ++j) ul[16 * w + jg * 4 + j] = su[j];
        }
        #pragma unroll
        for (int bj = 0; bj < 4; ++bj)
            #pragma unroll
            for (int j = 0; j < 4; ++j) {
                const int row = 16 * w + jg * 4 + j, col = 16 * bj + cl;
                OPH[1][row * 72 + col] = (unsigned short)bf16_rne_s(accA[bj][j]);
            }
    }
    __syncthreads();

    // ---- Ph4: R = A·SG^T + rank1 = A·G·S^T + rank1; rowmax -> aml ----
    {
        f32x4 acc[4];
        #pragma unroll
        for (int i = 0; i < 4; ++i) acc[i] = (f32x4){0.f, 0.f, 0.f, 0.f};
        mmStripe(OPH[1], OPH[5], 16 * w, acc);
        float mx[4] = {-3.4e38f, -3.4e38f, -3.4e38f, -3.4e38f};
        #pragma unroll
        for (int j = 0; j < 4; ++j) {
            const int row = 16 * w + jg * 4 + j;
            const float ur = ul[row], ar = avs[row];
            #pragma unroll
            for (int bj = 0; bj < 4; ++bj) {
                const int col = 16 * bj + cl;
                const float v = acc[bj][j] + ur * sbv[col] + ar * pls[col];
                mx[j] = fmaxf(mx[j], v);
            }
        }
        #pragma unroll
        for (int m = 1; m <= 8; m <<= 1)
            #pragma unroll
            for (int j = 0; j < 4; ++j) mx[j] = fmaxf(mx[j], __shfl_xor(mx[j], m));
        if (cl == 0) {
            #pragma unroll
            for (int j = 0; j < 4; ++j) aml[16 * w + jg * 4 + j] = mx[j];
        }
    }
    __syncthreads();

    // ---- Ph5: w_b = Wc·aml ----
    if (t < 64) {
        float s = 0.f;
        #pragma unroll 8
        for (int c = 0; c < 64; ++c) s += Wc[t * 64 + c] * aml[c];
        ws[WS_W + bb * 64 + t] = s;
    }
}

// ============ K3: out[b,o,n] = w[b,o] * v[b,n] (nontemporal, 2048 blocks) ============
__global__ __launch_bounds__(256) void k3(const float* __restrict__ ws, float* __restrict__ out) {
    const int blk = blockIdx.x;
    const int b = blk >> 6, seg = blk & 63;
    const int r0 = (seg >> 4) * 16, chk = seg & 15;
    __shared__ float wls[16];
    const int t = threadIdx.x;
    if (t < 16) wls[t] = ws[WS_W + b * 64 + r0 + t];
    __syncthreads();
    const size_t nb = (size_t)chk * 1024 + 4 * t;
    const f32x4 v4 = *(const f32x4*)(ws + WS_V + (size_t)b * N_ + nb);
    float* ob = out + ((size_t)b * C_ + r0) * N_ + nb;
    #pragma unroll
    for (int o = 0; o < 16; ++o) {
        __builtin_nontemporal_store(v4 * wls[o], (f32x4*)(ob + (size_t)o * N_));
    }
}

extern "C" void kernel_launch(void* const* d_in, const int* in_sizes, int n_in,
                              void* d_out, int out_size, void* d_ws, size_t ws_size,
                              hipStream_t stream) {
    const float* x     = (const float*)d_in[0];
    const float* Wq    = (const float*)d_in[1];
    const float* gamma = (const float*)d_in[3];
    const float* beta  = (const float*)d_in[4];
    const float* Wq2   = (const float*)d_in[5];
    const float* bq2   = (const float*)d_in[6];
    const float* Wsr   = (const float*)d_in[7];
    const float* bsr   = (const float*)d_in[8];
    const float* Wc    = (const float*)d_in[9];
    float* ws  = (float*)d_ws;
    float* out = (float*)d_out;

    hipLaunchKernelGGL(k1,  dim3(512),  dim3(512), 0, stream, x, ws);
    hipLaunchKernelGGL(k2a, dim3(256),  dim3(256), 0, stream, ws);
    hipLaunchKernelGGL(k2b, dim3(32),   dim3(256), 0, stream,
                       Wq, gamma, beta, Wq2, bq2, Wsr, bsr, Wc, ws);
    hipLaunchKernelGGL(k3,  dim3(2048), dim3(256), 0, stream, ws, out);
}